// Round 1
// baseline (284.984 us; speedup 1.0000x reference)
//
#include <hip/hip_runtime.h>
#include <hip/hip_bf16.h>

// MultiHeadSelfAttention  B=4 S=2048 H=16 Dh=64 Dm=1024 (fp32 in/out detected
// at runtime; intermediates bf16).
// Round 10:
//  - gemm_qkv replaced by gemm_qkv8: fused 8192x3072x1024 GEMM (Wq|Wk|Wv are
//    contiguous in wb), 256x256 tile, BK=64, 8 waves (2Mx4N), 128KB LDS
//    (2 K-tile slots), st_16x32 XOR swizzle on A/B tiles (linear
//    global_load_lds dest + inverse-swizzled global source + swizzled
//    ds_read offsets), 4 lockstep phases per K-tile {ds-reads | 1 half-tile
//    stage | s_barrier | lgkmcnt(0)+sched_barrier | setprio(1) 16x MFMA
//    setprio(0) | s_barrier}, counted s_waitcnt vmcnt(4) ONLY at group end
//    (before the closing barrier -> cross-wave staging visibility), never 0
//    in the main loop. Region-overwrite safety is barrier-ordered:
//    A(t+2) staged at ph4 (A(t) reads end ph3), B(t+1) staged ph1/2 into the
//    other slot. V epilogue writes vt transposed (bf16x4 along t) as before.
//  - gemm_out kept as m97 128^2 (N=1024 -> 256^2 would idle half the CUs).
// Keeps: R9 attn (S^T orientation, LDS K/VT tiles, max-free softmax,
// l = P@ones), XCD swizzle, cast pipeline, workspace layout.

typedef __bf16 bf16x8 __attribute__((ext_vector_type(8)));
typedef __bf16 bf16x4 __attribute__((ext_vector_type(4)));
typedef float  f32x4  __attribute__((ext_vector_type(4)));

#define SEQ 2048
#define NH  16
#define HD  64
#define DM  1024
#define RS  72

static __device__ __forceinline__ void gload_lds16(const __hip_bfloat16* g,
                                                   __hip_bfloat16* l) {
    __builtin_amdgcn_global_load_lds(
        (const __attribute__((address_space(1))) void*)g,
        (__attribute__((address_space(3))) void*)l, 16, 0, 0);
}

// ---------------------------------------------------------------------------
__global__ void detect_dtype_kernel(const unsigned short* __restrict__ x,
                                    int* __restrict__ flag) {
    if (threadIdx.x == 0 && blockIdx.x == 0) {
        int cnt = 0;
        for (int i = 0; i < 256; i += 2) {
            unsigned e = (x[i] >> 7) & 0xFFu;
            cnt += (e >= 0x70u && e <= 0x82u) ? 1 : 0;
        }
        *flag = (cnt >= 64) ? 0 : 1;   // 0 = bf16 data, 1 = fp32 data
    }
}

// ---------------------------------------------------------------------------
__global__ __launch_bounds__(256) void cast4_kernel(
    const void* __restrict__ src, __hip_bfloat16* __restrict__ dst,
    const int* __restrict__ flag, int n4)
{
    const int i = blockIdx.x * 256 + threadIdx.x;
    if (i >= n4) return;
    bf16x4 o;
    if (*flag) {
        f32x4 f = ((const f32x4*)src)[i];
        #pragma unroll
        for (int j = 0; j < 4; ++j) o[j] = (__bf16)f[j];
    } else {
        o = ((const bf16x4*)src)[i];
    }
    ((bf16x4*)dst)[i] = o;
}

__global__ __launch_bounds__(256) void cast4x3_kernel(
    const void* s0, const void* s1, const void* s2,
    __hip_bfloat16* d0, __hip_bfloat16* d1, __hip_bfloat16* d2,
    const int* __restrict__ flag, int n4)
{
    const int i = blockIdx.x * 256 + threadIdx.x;
    if (i >= n4) return;
    const void* s = (blockIdx.y == 0) ? s0 : (blockIdx.y == 1) ? s1 : s2;
    __hip_bfloat16* d = (blockIdx.y == 0) ? d0 : (blockIdx.y == 1) ? d1 : d2;
    bf16x4 o;
    if (*flag) {
        f32x4 f = ((const f32x4*)s)[i];
        #pragma unroll
        for (int j = 0; j < 4; ++j) o[j] = (__bf16)f[j];
    } else {
        o = ((const bf16x4*)s)[i];
    }
    ((bf16x4*)d)[i] = o;
}

// ---------------------------------------------------------------------------
// m97-style GEMM core (kept for gemm_out).
// ---------------------------------------------------------------------------
struct GemmCoord {
    int l15, g, wm, wn, r0, c0;
    int aRead, bRead;
};
static __device__ __forceinline__ GemmCoord gemm_coords() {
    GemmCoord c;
    const int tid = threadIdx.x;
    const int lane = tid & 63, wv = tid >> 6;
    c.l15 = lane & 15; c.g = lane >> 4;
    c.wm = wv >> 1;    c.wn = wv & 1;
    c.r0 = tid >> 2;   c.c0 = tid & 3;
    c.aRead = (c.wm * 64 + c.l15) * 32 + c.g * 8;
    c.bRead = (c.wn * 64 + c.l15) * 32 + c.g * 8;
    return c;
}

#define GEMM_BODY(Aptr, Bptr, m0v, n0v)                                        \
    __shared__ __hip_bfloat16 As[128 * 32];                                    \
    __shared__ __hip_bfloat16 Bs[128 * 32];                                    \
    const GemmCoord cc = gemm_coords();                                        \
    const int wv = threadIdx.x >> 6;                                           \
    const __hip_bfloat16* Ag0 = (Aptr) + (size_t)((m0v) + cc.r0) * DM + cc.c0 * 8;      \
    const __hip_bfloat16* Ag1 = (Aptr) + (size_t)((m0v) + cc.r0 + 64) * DM + cc.c0 * 8; \
    const __hip_bfloat16* Bg0 = (Bptr) + (size_t)((n0v) + cc.r0) * DM + cc.c0 * 8;      \
    const __hip_bfloat16* Bg1 = (Bptr) + (size_t)((n0v) + cc.r0 + 64) * DM + cc.c0 * 8; \
    __hip_bfloat16* AsD0 = As + 512 * wv;                                      \
    __hip_bfloat16* AsD1 = As + 2048 + 512 * wv;                               \
    __hip_bfloat16* BsD0 = Bs + 512 * wv;                                      \
    __hip_bfloat16* BsD1 = Bs + 2048 + 512 * wv;                               \
    f32x4 acc[4][4];                                                           \
    _Pragma("unroll") for (int i = 0; i < 4; ++i)                              \
        _Pragma("unroll") for (int j = 0; j < 4; ++j)                          \
            acc[i][j] = (f32x4){0.f, 0.f, 0.f, 0.f};                           \
    for (int kb = 0; kb < DM; kb += 32) {                                      \
        __syncthreads();                                                       \
        gload_lds16(Ag0 + kb, AsD0);                                           \
        gload_lds16(Ag1 + kb, AsD1);                                           \
        gload_lds16(Bg0 + kb, BsD0);                                           \
        gload_lds16(Bg1 + kb, BsD1);                                           \
        __syncthreads();                                                       \
        bf16x8 af[4], bfr[4];                                                  \
        _Pragma("unroll") for (int i = 0; i < 4; ++i)                          \
            af[i] = *reinterpret_cast<const bf16x8*>(&As[cc.aRead + i * 512]); \
        _Pragma("unroll") for (int j = 0; j < 4; ++j)                          \
            bfr[j] = *reinterpret_cast<const bf16x8*>(&Bs[cc.bRead + j * 512]);\
        _Pragma("unroll") for (int i = 0; i < 4; ++i)                          \
            _Pragma("unroll") for (int j = 0; j < 4; ++j)                      \
                acc[i][j] = __builtin_amdgcn_mfma_f32_16x16x32_bf16(           \
                    af[i], bfr[j], acc[i][j], 0, 0, 0);                        \
    }

// ---------------------------------------------------------------------------
// gemm_qkv8: fused QKV, 256x256 tile, BK=64, 8-phase counted-vmcnt schedule.
// A = xb [8192 x 1024], B = wb [3072 x 1024] (rows = output features).
// LDS (128KB dynamic): A[2 slots][2 halves][128x64], B likewise.
// Half-buffer layout: 16x32-element (16 rows x 64B) subtiles, 1024B each,
// subtile index = (row>>4)*2 + (kByte>>6); within: (row&15)*64 + (kByte&63);
// swizzle: byte ^= ((byte>>9)&1)<<5  (involution; applied on the global
// source side for staging and on the ds_read side for fragments).
// ---------------------------------------------------------------------------
__global__ __launch_bounds__(512, 2) void gemm_qkv8(
    const __hip_bfloat16* __restrict__ A,
    const __hip_bfloat16* __restrict__ Wb,
    const void* bq, const void* bk, const void* bv,
    __hip_bfloat16* q, __hip_bfloat16* kk, __hip_bfloat16* vt,
    const int* __restrict__ dflag)
{
    extern __shared__ __hip_bfloat16 lds[];
    __hip_bfloat16* Asl = lds;             // [2][2][8192] elements
    __hip_bfloat16* Bsl = lds + 32768;

    const int tid  = threadIdx.x;
    const int lane = tid & 63;
    const int wv   = tid >> 6;     // 0..7
    const int wm   = wv >> 2;      // 0..1  (M half)
    const int wn   = wv & 3;       // 0..3  (N quarter)
    const int l15  = lane & 15;
    const int g    = lane >> 4;

    // XCD-aware swizzle (384 % 8 == 0 -> simple form is bijective)
    const int bid = blockIdx.x;
    const int swz = (bid & 7) * 48 + (bid >> 3);
    const int mb  = swz / 12;
    const int nb  = swz % 12;
    const int m0  = mb * 256;
    const int n0  = nb * 256;

    // Staging source coords: thread phys byte = i*8192 + wv*1024 + lane*16
    // within a half-buffer; un-swizzle to get (row, col) in the 128x64 tile.
    int srow[2], scol[2];
    #pragma unroll
    for (int i = 0; i < 2; ++i) {
        const int sub = i * 8 + wv;                       // subtile 0..15
        srow[i] = (sub >> 1) * 16 + (lane >> 2);
        const int cb = (sub & 1) * 64 +
                       (((lane & 3) * 16) ^ ((lane & 32) ? 32 : 0));
        scol[i] = cb >> 1;                                // element col
    }
    // Fragment read offset (elements) within a half: subtile-local part.
    const int fr_e = l15 * 32 + ((g * 8) ^ ((l15 & 8) ? 16 : 0));

    const __hip_bfloat16* Bg = Wb + (size_t)n0 * DM;

    auto stageA = [&](int t, int h, int slot) {
        __hip_bfloat16* dst = Asl + slot * 16384 + h * 8192 + wv * 512;
        gload_lds16(A + (size_t)(m0 + h * 128 + srow[0]) * DM + t * 64 + scol[0], dst);
        gload_lds16(A + (size_t)(m0 + h * 128 + srow[1]) * DM + t * 64 + scol[1], dst + 4096);
    };
    auto stageB = [&](int t, int h, int slot) {
        __hip_bfloat16* dst = Bsl + slot * 16384 + h * 8192 + wv * 512;
        gload_lds16(Bg + (size_t)(h * 128 + srow[0]) * DM + t * 64 + scol[0], dst);
        gload_lds16(Bg + (size_t)(h * 128 + srow[1]) * DM + t * 64 + scol[1], dst + 4096);
    };

    f32x4 acc[8][4];
    #pragma unroll
    for (int m = 0; m < 8; ++m)
        #pragma unroll
        for (int n = 0; n < 4; ++n) acc[m][n] = (f32x4){0.f, 0.f, 0.f, 0.f};

    bf16x8 af[4][2];    // current m-quad (reused for m0..3 then m4..7)
    bf16x8 bfr[4][2];   // all 4 n frags of current tile

    // ---- prologue: tile0 full -> slot0, tile1 A -> slot1 (12 loads) ------
    stageA(0, 0, 0); stageA(0, 1, 0); stageB(0, 0, 0); stageB(0, 1, 0);
    stageA(1, 0, 1); stageA(1, 1, 1);
    asm volatile("s_waitcnt vmcnt(4)" ::: "memory");   // tile0 landed
    __builtin_amdgcn_s_barrier();

    for (int t = 0; t < 16; ++t) {
        const int slot = t & 1;
        const __hip_bfloat16* Ah = Asl + slot * 16384 + wm * 8192;
        const __hip_bfloat16* Bh = Bsl + slot * 16384 + (wn >> 1) * 8192 +
                                   (wn & 1) * 4096;

        // ---- phase 1: read A m0..3 + B n0,1; stage B1(t+1); MFMA m0-3 x n0-1
        #pragma unroll
        for (int m = 0; m < 4; ++m)
            #pragma unroll
            for (int kq = 0; kq < 2; ++kq)
                af[m][kq] = *reinterpret_cast<const bf16x8*>(
                    Ah + (m * 2 + kq) * 512 + fr_e);
        #pragma unroll
        for (int n = 0; n < 2; ++n)
            #pragma unroll
            for (int kq = 0; kq < 2; ++kq)
                bfr[n][kq] = *reinterpret_cast<const bf16x8*>(
                    Bh + (n * 2 + kq) * 512 + fr_e);
        if (t + 1 < 16) stageB(t + 1, 1, slot ^ 1);
        __builtin_amdgcn_s_barrier();
        asm volatile("s_waitcnt lgkmcnt(0)" ::: "memory");
        __builtin_amdgcn_sched_barrier(0);
        __builtin_amdgcn_s_setprio(1);
        #pragma unroll
        for (int m = 0; m < 4; ++m)
            #pragma unroll
            for (int n = 0; n < 2; ++n)
                #pragma unroll
                for (int kq = 0; kq < 2; ++kq)
                    acc[m][n] = __builtin_amdgcn_mfma_f32_16x16x32_bf16(
                        af[m][kq], bfr[n][kq], acc[m][n], 0, 0, 0);
        __builtin_amdgcn_s_setprio(0);
        __builtin_amdgcn_s_barrier();

        // ---- phase 2: read B n2,3; stage B0(t+1); MFMA m0-3 x n2-3 -------
        #pragma unroll
        for (int n = 2; n < 4; ++n)
            #pragma unroll
            for (int kq = 0; kq < 2; ++kq)
                bfr[n][kq] = *reinterpret_cast<const bf16x8*>(
                    Bh + (n * 2 + kq) * 512 + fr_e);
        if (t + 1 < 16) stageB(t + 1, 0, slot ^ 1);
        __builtin_amdgcn_s_barrier();
        asm volatile("s_waitcnt lgkmcnt(0)" ::: "memory");
        __builtin_amdgcn_sched_barrier(0);
        __builtin_amdgcn_s_setprio(1);
        #pragma unroll
        for (int m = 0; m < 4; ++m)
            #pragma unroll
            for (int n = 2; n < 4; ++n)
                #pragma unroll
                for (int kq = 0; kq < 2; ++kq)
                    acc[m][n] = __builtin_amdgcn_mfma_f32_16x16x32_bf16(
                        af[m][kq], bfr[n][kq], acc[m][n], 0, 0, 0);
        __builtin_amdgcn_s_setprio(0);
        __builtin_amdgcn_s_barrier();

        // ---- phase 3: read A m4..7 (reuse af regs); MFMA m4-7 x n0-1 -----
        #pragma unroll
        for (int m = 0; m < 4; ++m)
            #pragma unroll
            for (int kq = 0; kq < 2; ++kq)
                af[m][kq] = *reinterpret_cast<const bf16x8*>(
                    Ah + ((m + 4) * 2 + kq) * 512 + fr_e);
        __builtin_amdgcn_s_barrier();
        asm volatile("s_waitcnt lgkmcnt(0)" ::: "memory");
        __builtin_amdgcn_sched_barrier(0);
        __builtin_amdgcn_s_setprio(1);
        #pragma unroll
        for (int m = 0; m < 4; ++m)
            #pragma unroll
            for (int n = 0; n < 2; ++n)
                #pragma unroll
                for (int kq = 0; kq < 2; ++kq)
                    acc[m + 4][n] = __builtin_amdgcn_mfma_f32_16x16x32_bf16(
                        af[m][kq], bfr[n][kq], acc[m + 4][n], 0, 0, 0);
        __builtin_amdgcn_s_setprio(0);
        __builtin_amdgcn_s_barrier();

        // ---- phase 4: stage A0,A1(t+2) (A(t) reads ended ph3); MFMA
        //      m4-7 x n2-3; counted vmcnt BEFORE the closing barrier -------
        if (t + 2 < 16) { stageA(t + 2, 0, slot); stageA(t + 2, 1, slot); }
        __builtin_amdgcn_s_barrier();
        __builtin_amdgcn_s_setprio(1);
        #pragma unroll
        for (int m = 0; m < 4; ++m)
            #pragma unroll
            for (int n = 2; n < 4; ++n)
                #pragma unroll
                for (int kq = 0; kq < 2; ++kq)
                    acc[m + 4][n] = __builtin_amdgcn_mfma_f32_16x16x32_bf16(
                        af[m][kq], bfr[n][kq], acc[m + 4][n], 0, 0, 0);
        __builtin_amdgcn_s_setprio(0);
        if (t < 14)       asm volatile("s_waitcnt vmcnt(4)" ::: "memory");
        else if (t == 14) asm volatile("s_waitcnt vmcnt(0)" ::: "memory");
        __builtin_amdgcn_s_barrier();
    }

    // ---- epilogue --------------------------------------------------------
    const int widx = nb >> 2;                 // 0=q 1=k 2=v
    const bool f32 = (*dflag != 0);
    const void* bias = (widx == 0) ? bq : (widx == 1) ? bk : bv;

    if (widx == 2) {
        #pragma unroll
        for (int n = 0; n < 4; ++n) {
            const int col = (nb & 3) * 256 + wn * 64 + n * 16 + l15;
            const float bvv = f32 ? ((const float*)bias)[col]
                                  : __bfloat162float(((const __hip_bfloat16*)bias)[col]);
            #pragma unroll
            for (int m = 0; m < 8; ++m) {
                const int row0 = m0 + wm * 128 + m * 16 + g * 4;
                const int bb = row0 >> 11;
                const int tt = row0 & 2047;
                bf16x4 pv;
                #pragma unroll
                for (int r = 0; r < 4; ++r)
                    pv[r] = (__bf16)(acc[m][n][r] + bvv);
                *reinterpret_cast<bf16x4*>(
                    vt + (size_t)(bb * 1024 + col) * SEQ + tt) = pv;
            }
        }
    } else {
        __hip_bfloat16* out = (widx == 0) ? q : kk;
        #pragma unroll
        for (int n = 0; n < 4; ++n) {
            const int col = (nb & 3) * 256 + wn * 64 + n * 16 + l15;
            const float bvv = f32 ? ((const float*)bias)[col]
                                  : __bfloat162float(((const __hip_bfloat16*)bias)[col]);
            #pragma unroll
            for (int m = 0; m < 8; ++m) {
                #pragma unroll
                for (int r = 0; r < 4; ++r) {
                    const int row = m0 + wm * 128 + m * 16 + g * 4 + r;
                    out[(size_t)row * DM + col] = __float2bfloat16(acc[m][n][r] + bvv);
                }
            }
        }
    }
}

__global__ __launch_bounds__(256) void gemm_out(
    const __hip_bfloat16* __restrict__ A,
    const __hip_bfloat16* __restrict__ B,
    const void* bias, void* __restrict__ outv,
    const int* __restrict__ dflag)
{
    const int m0 = blockIdx.x * 128;
    const int n0 = blockIdx.y * 128;
    const bool f32 = (*dflag != 0);

    GEMM_BODY(A, B, m0, n0)

    #pragma unroll
    for (int j = 0; j < 4; ++j) {
        const int col = n0 + cc.wn * 64 + j * 16 + cc.l15;
        const float bvv = f32 ? ((const float*)bias)[col]
                              : __bfloat162float(((const __hip_bfloat16*)bias)[col]);
        #pragma unroll
        for (int i = 0; i < 4; ++i) {
            #pragma unroll
            for (int r = 0; r < 4; ++r) {
                const int row = m0 + cc.wm * 64 + i * 16 + cc.g * 4 + r;
                const float val = acc[i][j][r] + bvv;
                if (f32) ((float*)outv)[(size_t)row * DM + col] = val;
                else ((__hip_bfloat16*)outv)[(size_t)row * DM + col] = __float2bfloat16(val);
            }
        }
    }
}

// ---------------------------------------------------------------------------
// Flash attention (S^T orientation) — unchanged from R9.
// ---------------------------------------------------------------------------
__global__ __launch_bounds__(256) void attn_flash_mfma(
    const __hip_bfloat16* __restrict__ q,
    const __hip_bfloat16* __restrict__ k,
    const __hip_bfloat16* __restrict__ vt,   // [b][h][d][t]
    __hip_bfloat16* __restrict__ ctx)
{
    __shared__ __hip_bfloat16 Ks[64 * HD];        // 8KB swizzled K tile
    __shared__ __hip_bfloat16 Vs[HD * 64];        // 8KB swizzled VT tile
    __shared__ __hip_bfloat16 P[4][16 * RS];      // per-wave P (9.2KB)

    const int tid  = threadIdx.x;
    const int lane = tid & 63;
    const int wave = tid >> 6;
    const int g    = lane >> 4;
    const int l15  = lane & 15;
    const int l7   = l15 & 7;

    const int lid  = blockIdx.x;
    const int xcd  = lid & 7;
    const int slot = lid >> 3;
    const int p    = (slot >> 4) * 8 + xcd;   // 0..63 = b*16+h
    const int qp   = slot & 15;
    const int b    = p >> 4;
    const int h    = p & 15;

    const size_t hb = (size_t)b * SEQ * DM + (size_t)h * HD;
    const __hip_bfloat16* vth = vt + (size_t)(b * NH + h) * HD * SEQ;
    __hip_bfloat16* Pw = P[wave];

    const int c0  = wave * 64 + lane;
    const int c1  = 256 + wave * 64 + lane;
    const int kr0 = c0 >> 3, ks0 = ((c0 & 7) ^ (kr0 & 7)) * 8;
    const int kr1 = c1 >> 3, ks1 = ((c1 & 7) ^ (kr1 & 7)) * 8;
    __hip_bfloat16* KsD0 = Ks + wave * 512;
    __hip_bfloat16* KsD1 = Ks + 2048 + wave * 512;
    __hip_bfloat16* VsD0 = Vs + wave * 512;
    __hip_bfloat16* VsD1 = Vs + 2048 + wave * 512;

    const int f0off = ((g ^ l7)) * 8;
    const int f1off = (((4 + g) ^ l7)) * 8;

    bf16x8 ones;
    #pragma unroll
    for (int j = 0; j < 8; ++j) ones[j] = (__bf16)1.0f;

    #pragma unroll
    for (int half = 0; half < 2; ++half) {
        const int qt = half ? (SEQ / 64 - 1 - qp) : qp;
        const int q0 = qt * 64;

        const int qrow = q0 + wave * 16 + l15;
        const __hip_bfloat16* qp_ = q + hb + (size_t)qrow * DM + g * 8;
        bf16x8 qf0 = *reinterpret_cast<const bf16x8*>(qp_);
        bf16x8 qf1 = *reinterpret_cast<const bf16x8*>(qp_ + 32);
        #pragma unroll
        for (int j = 0; j < 8; ++j) {
            qf0[j] = (__bf16)((float)qf0[j] * 0.125f);   // 1/sqrt(64)
            qf1[j] = (__bf16)((float)qf1[j] * 0.125f);
        }

        f32x4 o[4];
        #pragma unroll
        for (int j = 0; j < 4; ++j) o[j] = (f32x4){0.f, 0.f, 0.f, 0.f};
        f32x4 zl = (f32x4){0.f, 0.f, 0.f, 0.f};   // row sums of P

        for (int kt = 0; kt <= qt; ++kt) {
            const int kbase = kt * 64;

            __syncthreads();
            gload_lds16(k + hb + (size_t)(kbase + kr0) * DM + ks0, KsD0);
            gload_lds16(k + hb + (size_t)(kbase + kr1) * DM + ks1, KsD1);
            gload_lds16(vth + (size_t)kr0 * SEQ + kbase + ks0, VsD0);
            gload_lds16(vth + (size_t)kr1 * SEQ + kbase + ks1, VsD1);
            __syncthreads();

            f32x4 s[4];
            #pragma unroll
            for (int j = 0; j < 4; ++j) {
                const int krow = (j * 16 + l15) * 64;
                bf16x8 kf0 = *reinterpret_cast<const bf16x8*>(&Ks[krow + f0off]);
                bf16x8 kf1 = *reinterpret_cast<const bf16x8*>(&Ks[krow + f1off]);
                f32x4 z = (f32x4){0.f, 0.f, 0.f, 0.f};
                z = __builtin_amdgcn_mfma_f32_16x16x32_bf16(kf0, qf0, z, 0, 0, 0);
                z = __builtin_amdgcn_mfma_f32_16x16x32_bf16(kf1, qf1, z, 0, 0, 0);
                s[j] = z;
            }

            if (kt == qt) {
                const int qq = wave * 16 + l15;
                #pragma unroll
                for (int j = 0; j < 4; ++j) {
                    #pragma unroll
                    for (int r = 0; r < 4; ++r) {
                        const int key = j * 16 + g * 4 + r;
                        if (key > qq) s[j][r] = -1e30f;
                    }
                }
            }

            #pragma unroll
            for (int j = 0; j < 4; ++j)
                #pragma unroll
                for (int r = 0; r < 4; ++r)
                    s[j][r] = __expf(s[j][r]);

            #pragma unroll
            for (int j = 0; j < 4; ++j) {
                bf16x4 pv;
                #pragma unroll
                for (int r = 0; r < 4; ++r) pv[r] = (__bf16)s[j][r];
                *reinterpret_cast<bf16x4*>(&Pw[l15 * RS + j * 16 + g * 4]) = pv;
            }

            const bf16x8 a0 = *reinterpret_cast<const bf16x8*>(&Pw[l15 * RS + g * 8]);
            const bf16x8 a1 = *reinterpret_cast<const bf16x8*>(&Pw[l15 * RS + 32 + g * 8]);

            zl = __builtin_amdgcn_mfma_f32_16x16x32_bf16(a0, ones, zl, 0, 0, 0);
            zl = __builtin_amdgcn_mfma_f32_16x16x32_bf16(a1, ones, zl, 0, 0, 0);

            #pragma unroll
            for (int jd = 0; jd < 4; ++jd) {
                const int vrow = (jd * 16 + l15) * 64;
                const bf16x8 b0 = *reinterpret_cast<const bf16x8*>(&Vs[vrow + f0off]);
                const bf16x8 b1 = *reinterpret_cast<const bf16x8*>(&Vs[vrow + f1off]);
                o[jd] = __builtin_amdgcn_mfma_f32_16x16x32_bf16(a0, b0, o[jd], 0, 0, 0);
                o[jd] = __builtin_amdgcn_mfma_f32_16x16x32_bf16(a1, b1, o[jd], 0, 0, 0);
            }
        }

        #pragma unroll
        for (int r = 0; r < 4; ++r) {
            const float inv = 1.f / zl[r];
            const int sq = q0 + wave * 16 + g * 4 + r;
            #pragma unroll
            for (int jd = 0; jd < 4; ++jd)
                ctx[hb + (size_t)sq * DM + jd * 16 + l15] =
                    __float2bfloat16(o[jd][r] * inv);
        }
    }
}

// ---------------------------------------------------------------------------
extern "C" void kernel_launch(void* const* d_in, const int* in_sizes, int n_in,
                              void* d_out, int out_size, void* d_ws, size_t ws_size,
                              hipStream_t stream) {
    const int M = 4 * SEQ;   // 8192

    // size-based input mapping
    int xi = 0, wi[4] = {-1, -1, -1, -1}, bi[4] = {-1, -1, -1, -1};
    int nw = 0, nb = 0;
    for (int i = 0; i < n_in; ++i) {
        if (in_sizes[i] == 4 * SEQ * DM) xi = i;
        else if (in_sizes[i] == DM * DM && nw < 4) wi[nw++] = i;
        else if (in_sizes[i] == DM && nb < 4) bi[nb++] = i;
    }
    if (nw < 4 || nb < 4) {
        const int wOff = n_in - 8;
        for (int j = 0; j < 4; ++j) { wi[j] = wOff + 2 * j; bi[j] = wOff + 2 * j + 1; }
    }
    const void* x  = d_in[xi];
    const void* W[4]  = {d_in[wi[0]], d_in[wi[1]], d_in[wi[2]], d_in[wi[3]]};
    const void* Bs[4] = {d_in[bi[0]], d_in[bi[1]], d_in[bi[2]], d_in[bi[3]]};

    // ws: q | kk | vt | flag. ctx aliases q.
    const size_t mat = (size_t)M * DM;
    __hip_bfloat16* q   = (__hip_bfloat16*)d_ws;
    __hip_bfloat16* kk  = q + mat;
    __hip_bfloat16* vt  = kk + mat;
    __hip_bfloat16* ctx = q;
    int* flag = (int*)((char*)d_ws + 3 * mat * sizeof(__hip_bfloat16));

    // d_out scratch: xb (16.78 MB) + wb (6.29 MB); both dead before gemm_out.
    __hip_bfloat16* xb  = (__hip_bfloat16*)d_out;
    __hip_bfloat16* wb  = xb + mat;
    __hip_bfloat16* wob = kk;                       // Wo bf16, after attention

    static bool s_attr = false;
    if (!s_attr) {
        (void)hipFuncSetAttribute((const void*)gemm_qkv8,
                                  hipFuncAttributeMaxDynamicSharedMemorySize,
                                  131072);
        s_attr = true;
    }

    detect_dtype_kernel<<<1, 64, 0, stream>>>((const unsigned short*)x, flag);

    cast4_kernel<<<dim3((int)(mat / 4 / 256)), 256, 0, stream>>>(x, xb, flag, (int)(mat / 4));
    cast4x3_kernel<<<dim3(DM * DM / 4 / 256, 3), 256, 0, stream>>>(
        W[0], W[1], W[2], wb, wb + (size_t)DM * DM, wb + 2 * (size_t)DM * DM,
        flag, DM * DM / 4);

    gemm_qkv8<<<dim3(384), 512, 131072, stream>>>(
        xb, wb, Bs[0], Bs[1], Bs[2], q, kk, vt, flag);

    attn_flash_mfma<<<dim3(1024), 256, 0, stream>>>(q, kk, vt, ctx);

    cast4_kernel<<<dim3(DM * DM / 4 / 256), 256, 0, stream>>>(W[3], wob, flag, DM * DM / 4);

    gemm_out<<<dim3(M / 128, DM / 128), 256, 0, stream>>>(ctx, wob, Bs[3], d_out, flag);
}